// Round 16
// baseline (236.564 us; speedup 1.0000x reference)
//
#include <hip/hip_runtime.h>
#include <stdint.h>
#include <math.h>

#define B_   4
#define L_   2048
#define H_   16
#define DH_  64
#define DM_  1024

typedef __bf16 bf16;
typedef __attribute__((ext_vector_type(8))) __bf16 bf16x8;
typedef __attribute__((ext_vector_type(4))) float f32x4;
typedef __attribute__((ext_vector_type(4))) int i32x4;
typedef __attribute__((ext_vector_type(4))) short s16x4;
typedef unsigned short u16;
typedef unsigned int u32;
typedef __attribute__((ext_vector_type(2))) unsigned int u32x2;
typedef __attribute__((ext_vector_type(4))) unsigned short u16x4;

typedef unsigned int u32g __attribute__((address_space(1)));
typedef unsigned int u32l __attribute__((address_space(3)));

__device__ __forceinline__ u16 f2bf(float f) {
  return __builtin_bit_cast(u16, (bf16)f);   // fptrunc = RNE
}

// 2^x via the HW transcendental unit (scores are kept in log2 units)
__device__ __forceinline__ float exp2_fast(float x) {
  float r; asm("v_exp_f32 %0, %1" : "=v"(r) : "v"(x)); return r;
}

// async global->LDS 16B; LDS dest must be wave-uniform base + lane*16
__device__ __forceinline__ void gload16(const void* g, void* l) {
  __builtin_amdgcn_global_load_lds((const u32g*)g, (u32l*)l, 16, 0, 0);
}

// K=16 bf16 MFMA: A/B are 4 bf16 per lane with k=(lane>>4)*4+j — this matches
// the C-layout of the QK 16x16x32 MFMA, so P needs NO cross-lane transpose.
__device__ __forceinline__ f32x4 mfma16(s16x4 a, s16x4 b, f32x4 c) {
#if __has_builtin(__builtin_amdgcn_mfma_f32_16x16x16bf16_1k)
  return __builtin_amdgcn_mfma_f32_16x16x16bf16_1k(a, b, c, 0, 0, 0);
#else
  asm volatile("v_mfma_f32_16x16x16_bf16 %0, %1, %2, %0\n\ts_nop 7\n\ts_nop 2"
               : "+v"(c) : "v"(a), "v"(b));
  return c;
#endif
}

// ---------------- fused f32 -> bf16 conversion + bias table (one launch) ----------------
#define NX4 2097152                  // 8192*1024/4
#define NQ4 786432                   // 3072*1024/4
#define NO4 262144                   // 1024*1024/4
#define NTOT4 (NX4 + NQ4 + NO4)      // 3145728
__global__ __launch_bounds__(256) void cvt3b(const float* __restrict__ x,
                                             const float* __restrict__ wq,
                                             const float* __restrict__ wo,
                                             u16* __restrict__ xb, u16* __restrict__ wqb,
                                             u16* __restrict__ wob,
                                             const float* __restrict__ ts,
                                             const float* __restrict__ msk,
                                             const float* __restrict__ decay,
                                             float* __restrict__ Bk) {
  int i = blockIdx.x * 256 + threadIdx.x;    // grid = NTOT4 + 64*2048 threads
  if (i >= NTOT4) {
    int j = i - NTOT4;                       // 0 .. 131071
    int bh = j >> 11, l = j & (L_ - 1);
    int b = bh >> 4, h = bh & 15;
    float dc24 = log1pf(__expf(decay[h])) * (1.0f / 24.0f) * 1.44269504f;
    float tv = ts[b * L_ + l], mv = msk[b * L_ + l];
    Bk[j] = (mv != 0.f) ? dc24 * tv : -INFINITY;
    return;
  }
  const float* src; u16* dst; int j;
  if (i < NX4)            { src = x;  dst = xb;  j = i; }
  else if (i < NX4 + NQ4) { src = wq; dst = wqb; j = i - NX4; }
  else                    { src = wo; dst = wob; j = i - NX4 - NQ4; }
  f32x4 v = ((const f32x4*)src)[j];
  u16x4 o;
  o[0] = f2bf(v[0]); o[1] = f2bf(v[1]); o[2] = f2bf(v[2]); o[3] = f2bf(v[3]);
  ((u16x4*)dst)[j] = o;
}

// ---------------- QKV GEMM R25: A via LDS, B DIRECT FROM GLOBAL (L2-hot) ----------------
// LDS-BW model from R24 counters: per tile per CU, LDS reads = A 128KB (4x
// wave amplification) + B 64KB (2x) = 192 b128 x ~12cyc ~ 2300cyc vs MFMA
// 640cyc -> MfmaUtil ceiling 28%; measured 26.4%. Schedule can't fix bytes.
// Fix: B fragments load straight global->reg (weights are L2-hot; panel
// 512KB/block). LDS now A-only: ~1536cyc/tile (-33% on binding resource).
//  * B banks bfrA/bfrB strict per-phase ping-pong (32 VGPR, register-neutral
//    vs staged bfr[4][2]): P1 consume A issue B(hi); P2 consume B issue
//    A(hi'); P3 consume A issue B(lo'); P4 consume B issue A(lo,t+1).
//    Invariant: after P4 bankA holds lo(t+1) -> P1 always consumes bankA.
//  * A staging (gload_lds): SA(t+2,q0,q2)@P2, SA(t+2,q1,q3)@P4 into buffer
//    t&1 — regions' readers drained at P1/P3 lgkm0 (same proof as R20).
//  * Per-phase counted waits (all "memory" asm so counts are stable):
//    P1: vmcnt(4)+lgkm0 (newer = 4 B); P2: vmcnt(6|4) (4 B + 2|0 SA);
//    P3: vmcnt(4)+lgkm0; P4: vmcnt(6|4|0). At t.P4's wait, SA(t+1) (issued
//    t-1.P2/P4, >=20 vmem older) is forced complete before t+1.P1 ds_reads.
//  * B address = pre-swizzle identity: old path returned granule kk*4+g of
//    row; direct load reads B[n0+row][k0 + (kk*4+g)*8] (16B aligned).
__global__ __launch_bounds__(512) void gemm_qkv(
    const u16* __restrict__ A, const u16* __restrict__ Bm, const float* __restrict__ bias,
    u16* __restrict__ Qb, u16* __restrict__ Kb, u16* __restrict__ Vt)
{
  __shared__ char smem[135168];     // staging: 2 x A 32KB = 64KB; epi ltr[256][264]
  u16* ltr = (u16*)smem;
  const int K = 1024, nk = 16;

  const int tid = threadIdx.x;
  const int nwg = gridDim.x;              // 384, %8==0
  int idx = blockIdx.x;
  idx = (idx & 7) * (nwg >> 3) + (idx >> 3);
  const int nbx = 12;                     // N=3072 / 256
  const int bx = idx % nbx, by = idx / nbx;
  const int m0 = by << 8, n0 = bx << 8;

  const int lane = tid & 63, w = tid >> 6;
  const int g = lane >> 4, col = lane & 15;
  const int wr = w >> 2, wc = w & 3;      // 2M x 4N; per-wave C = 128 x 64

  f32x4 acc[8][4];
#pragma unroll
  for (int mt = 0; mt < 8; ++mt)
#pragma unroll
    for (int nt = 0; nt < 4; ++nt) {
      acc[mt][nt][0] = 0.f; acc[mt][nt][1] = 0.f;
      acc[mt][nt][2] = 0.f; acc[mt][nt][3] = 0.f;
    }

  // stage A quarter q (rows q*64..q*64+63) of tile kt into buf nb — 1 load/thread
  auto SA = [&](int kt, int nb, int q) {
    char* dA = smem + (nb << 15);
    int c = (q << 9) + tid;
    int row = c >> 3, cc = c & 7;
    gload16(A + (size_t)(m0 + row) * K + (kt << 6) + ((cc ^ (row & 7)) << 3), dA + c * 16);
  };

  auto RDA = [&](const char* bA, int mt, int kk) {
    int row = wr * 128 + mt * 16 + col;
    return *(const bf16x8*)(bA + row * 128 + ((((kk << 2) + g) ^ (row & 7)) << 4));
  };

  bf16x8 af[4][2], bfrA[2][2], bfrB[2][2];

  // B fragment set direct from global: half=0 -> n-frags 0,1; half=1 -> 2,3
  auto LDB = [&](bf16x8 (&bank)[2][2], int kt, int half) {
    const int k0 = kt << 6;
#pragma unroll
    for (int n2 = 0; n2 < 2; ++n2)
#pragma unroll
      for (int kk = 0; kk < 2; ++kk) {
        int row = wc * 64 + (half * 2 + n2) * 16 + col;
        bank[n2][kk] = *(const bf16x8*)(Bm + (size_t)(n0 + row) * K + k0 + (((kk << 2) + g) << 3));
      }
  };

  // ---- prologue: A tiles 0,1 staged; B lo(0) in flight ----
  SA(0, 0, 0); SA(0, 0, 1); SA(0, 0, 2); SA(0, 0, 3);
  LDB(bfrA, 0, 0);
  SA(1, 1, 0); SA(1, 1, 1); SA(1, 1, 2); SA(1, 1, 3);
  asm volatile("s_waitcnt vmcnt(4)" ::: "memory");   // SA0 + bfrA landed; SA1 in flight
  __builtin_amdgcn_s_barrier();

  for (int t = 0; t < nk; ++t) {
    const char* bufA = smem + ((t & 1) << 15);
    const int nbC = t & 1;                // buffer of tile t+2 (== current's)

    // ---- P1: m-lo x n-lo (consume bankA=lo(t)); issue bankB=hi(t) ----
#pragma unroll
    for (int mi = 0; mi < 4; ++mi) { af[mi][0] = RDA(bufA, mi, 0); af[mi][1] = RDA(bufA, mi, 1); }
    LDB(bfrB, t, 1);
    __builtin_amdgcn_s_barrier();
    asm volatile("s_waitcnt vmcnt(4) lgkmcnt(0)" ::: "memory");
    __builtin_amdgcn_sched_barrier(0);
    __builtin_amdgcn_s_setprio(1);
#pragma unroll
    for (int mi = 0; mi < 4; ++mi)
#pragma unroll
      for (int ni = 0; ni < 2; ++ni)
#pragma unroll
        for (int kk = 0; kk < 2; ++kk)
          acc[mi][ni] = __builtin_amdgcn_mfma_f32_16x16x32_bf16(af[mi][kk], bfrA[ni][kk], acc[mi][ni], 0, 0, 0);
    __builtin_amdgcn_s_setprio(0);
    __builtin_amdgcn_s_barrier();

    // ---- P2: m-lo x n-hi (consume bankB=hi(t)); issue bankA=hi(t)'; SA q0,q2 ----
    LDB(bfrA, t, 1);
    if (t + 2 < nk) { SA(t + 2, nbC, 0); SA(t + 2, nbC, 2); }
    __builtin_amdgcn_s_barrier();
    if (t + 2 < nk) asm volatile("s_waitcnt vmcnt(6)" ::: "memory");
    else            asm volatile("s_waitcnt vmcnt(4)" ::: "memory");
    __builtin_amdgcn_sched_barrier(0);
    __builtin_amdgcn_s_setprio(1);
#pragma unroll
    for (int mi = 0; mi < 4; ++mi)
#pragma unroll
      for (int ni = 0; ni < 2; ++ni)
#pragma unroll
        for (int kk = 0; kk < 2; ++kk)
          acc[mi][ni + 2] = __builtin_amdgcn_mfma_f32_16x16x32_bf16(af[mi][kk], bfrB[ni][kk], acc[mi][ni + 2], 0, 0, 0);
    __builtin_amdgcn_s_setprio(0);
    __builtin_amdgcn_s_barrier();

    // ---- P3: m-hi x n-hi (consume bankA=hi'); read af m-hi; issue bankB=lo(t)' ----
#pragma unroll
    for (int mi = 0; mi < 4; ++mi) { af[mi][0] = RDA(bufA, mi + 4, 0); af[mi][1] = RDA(bufA, mi + 4, 1); }
    LDB(bfrB, t, 0);
    __builtin_amdgcn_s_barrier();
    asm volatile("s_waitcnt vmcnt(4) lgkmcnt(0)" ::: "memory");
    __builtin_amdgcn_sched_barrier(0);
    __builtin_amdgcn_s_setprio(1);
#pragma unroll
    for (int mi = 0; mi < 4; ++mi)
#pragma unroll
      for (int ni = 0; ni < 2; ++ni)
#pragma unroll
        for (int kk = 0; kk < 2; ++kk)
          acc[mi + 4][ni + 2] = __builtin_amdgcn_mfma_f32_16x16x32_bf16(af[mi][kk], bfrA[ni][kk], acc[mi + 4][ni + 2], 0, 0, 0);
    __builtin_amdgcn_s_setprio(0);
    __builtin_amdgcn_s_barrier();

    // ---- P4: m-hi x n-lo (consume bankB=lo'); issue bankA=lo(t+1); SA q1,q3 ----
    if (t + 1 < nk) LDB(bfrA, t + 1, 0);
    if (t + 2 < nk) { SA(t + 2, nbC, 1); SA(t + 2, nbC, 3); }
    if (t + 2 < nk)      asm volatile("s_waitcnt vmcnt(6)" ::: "memory");
    else if (t + 1 < nk) asm volatile("s_waitcnt vmcnt(4)" ::: "memory");
    else                 asm volatile("s_waitcnt vmcnt(0)" ::: "memory");
    __builtin_amdgcn_sched_barrier(0);
    __builtin_amdgcn_s_setprio(1);
#pragma unroll
    for (int mi = 0; mi < 4; ++mi)
#pragma unroll
      for (int ni = 0; ni < 2; ++ni)
#pragma unroll
        for (int kk = 0; kk < 2; ++kk)
          acc[mi + 4][ni] = __builtin_amdgcn_mfma_f32_16x16x32_bf16(af[mi][kk], bfrB[ni][kk], acc[mi + 4][ni], 0, 0, 0);
    __builtin_amdgcn_s_setprio(0);
    __builtin_amdgcn_s_barrier();
  }

  // ---- mode-0 epilogue via padded LDS transpose: ltr[256][264] u16 ----
  const int type = n0 >> 10;
  const float qsc = (type == 0) ? 0.125f * 1.44269504f : 1.0f;
#pragma unroll
  for (int nt = 0; nt < 4; ++nt) {
    int nn = wc * 64 + nt * 16 + col;
    float bv = bias[n0 + nn];
#pragma unroll
    for (int mt = 0; mt < 8; ++mt) {
      int mm = wr * 128 + mt * 16 + g * 4;
#pragma unroll
      for (int r = 0; r < 4; ++r) {
        u16 hv = f2bf((acc[mt][nt][r] + bv) * qsc);
        if (type < 2) ltr[(mm + r) * 264 + nn] = hv;
        else          ltr[nn * 264 + (mm + r)] = hv;
      }
    }
  }
  __syncthreads();
  if (type < 2) {
#pragma unroll
    for (int it = 0; it < 16; ++it) {
      int cid = tid + it * 512;
      int rrow = cid >> 5, cc = cid & 31;
      i32x4 v = *(const i32x4*)((const char*)ltr + rrow * 528 + cc * 16);
      int token = m0 + rrow;
      int bb = token >> 11, ll = token & (L_ - 1);
      int gn = n0 + cc * 8;
      int head = (gn & 1023) >> 6, d = gn & 63;
      u16* dst = (type == 0) ? Qb : Kb;
      *(i32x4*)(dst + ((size_t)((bb * H_ + head) * L_ + ll)) * 64 + d) = v;
    }
  } else {
#pragma unroll
    for (int it = 0; it < 16; ++it) {
      int cid = tid + it * 512;
      int rrow = cid >> 5, cc = cid & 31;
      i32x4 v = *(const i32x4*)((const char*)ltr + rrow * 528 + cc * 16);
      int gn = n0 + rrow;
      int head = (gn & 1023) >> 6, d = gn & 63;
      int token0 = m0 + cc * 8;
      int bb = token0 >> 11, ll = token0 & (L_ - 1);
      *(i32x4*)(Vt + ((size_t)((bb * H_ + head) * DH_ + d)) * L_ + ll) = v;
    }
  }
}

// ---------------- bf16 GEMM (R17 verbatim — mode-1 output GEMM) ----------------
__global__ __launch_bounds__(512) void gemm_bf16(
    const u16* __restrict__ A, const u16* __restrict__ Bm, const float* __restrict__ bias,
    int M, int N, int K, int mode,
    u16* __restrict__ Qb, u16* __restrict__ Kb, u16* __restrict__ Vt, float* __restrict__ Cout)
{
  __shared__ char smem[147456];
  const int tid = threadIdx.x;
  const int nwg = gridDim.x;
  int idx = blockIdx.x;
  idx = (idx & 7) * (nwg >> 3) + (idx >> 3);
  const int nbx = N >> 7;
  const int bx = idx % nbx, by = idx / nbx;
  const int m0 = by << 8, n0 = bx << 7;

  const int lane = tid & 63, w = tid >> 6;
  const int g = lane >> 4, col = lane & 15;
  const int wr = w >> 1, wc = w & 1;

  f32x4 acc[4][4];
#pragma unroll
  for (int mt = 0; mt < 4; ++mt)
#pragma unroll
    for (int nt = 0; nt < 4; ++nt) {
      acc[mt][nt][0] = 0.f; acc[mt][nt][1] = 0.f;
      acc[mt][nt][2] = 0.f; acc[mt][nt][3] = 0.f;
    }

  auto STAGE_A = [&](int kt, int nb, int hh) {
    char* dA = smem + nb * 49152;
    const int k0 = kt << 6;
#pragma unroll
    for (int pp = hh * 2; pp < hh * 2 + 2; ++pp) {
      int c = tid + pp * 512;
      int row = c >> 3, cc = c & 7;
      gload16(A + (size_t)(m0 + row) * K + k0 + ((cc ^ (row & 7)) << 3), dA + c * 16);
    }
  };
  auto STAGE_B = [&](int kt, int nb) {
    char* dB = smem + nb * 49152 + 32768;
    const int k0 = kt << 6;
#pragma unroll
    for (int pp = 0; pp < 2; ++pp) {
      int c = tid + pp * 512;
      int row = c >> 3, cc = c & 7;
      gload16(Bm + (size_t)(n0 + row) * K + k0 + ((cc ^ (row & 7)) << 3), dB + c * 16);
    }
  };

  STAGE_A(0, 0, 0); STAGE_A(0, 0, 1); STAGE_B(0, 0);
  STAGE_A(1, 1, 0); STAGE_A(1, 1, 1); STAGE_B(1, 1);
  asm volatile("s_waitcnt vmcnt(6)" ::: "memory");
  __builtin_amdgcn_s_barrier();

  const int nk = K >> 6;
  for (int t = 0; t < nk; ++t) {
    const char* bufA = smem + (t % 3) * 49152;
    const char* bufB = bufA + 32768;
    const bool pf = (t + 2 < nk);
    const int nb2 = (t + 2) % 3;

    bf16x8 af[4][2], bfr[4][2];
    auto RDA = [&](int mt, int kk) {
      int row = wr * 64 + mt * 16 + col;
      return *(const bf16x8*)(bufA + row * 128 + ((((kk << 2) + g) ^ (row & 7)) << 4));
    };
    auto RDB = [&](int nt, int kk) {
      int row = wc * 64 + nt * 16 + col;
      return *(const bf16x8*)(bufB + row * 128 + ((((kk << 2) + g) ^ (row & 7)) << 4));
    };
    auto QUAD = [&](int qm, int qn) {
      __builtin_amdgcn_s_setprio(1);
#pragma unroll
      for (int mi = 0; mi < 2; ++mi)
#pragma unroll
        for (int ni = 0; ni < 2; ++ni)
#pragma unroll
          for (int kk = 0; kk < 2; ++kk)
            acc[qm * 2 + mi][qn * 2 + ni] = __builtin_amdgcn_mfma_f32_16x16x32_bf16(
                af[qm * 2 + mi][kk], bfr[qn * 2 + ni][kk], acc[qm * 2 + mi][qn * 2 + ni], 0, 0, 0);
      __builtin_amdgcn_s_setprio(0);
    };

#pragma unroll
    for (int mi = 0; mi < 2; ++mi) { af[mi][0] = RDA(mi, 0); af[mi][1] = RDA(mi, 1); }
#pragma unroll
    for (int ni = 0; ni < 2; ++ni) { bfr[ni][0] = RDB(ni, 0); bfr[ni][1] = RDB(ni, 1); }
    if (pf) STAGE_A(t + 2, nb2, 0);
    __builtin_amdgcn_s_barrier();
    asm volatile("s_waitcnt lgkmcnt(0)" ::: "memory");
    __builtin_amdgcn_sched_barrier(0);
    QUAD(0, 0);
    __builtin_amdgcn_s_barrier();

#pragma unroll
    for (int ni = 2; ni < 4; ++ni) { bfr[ni][0] = RDB(ni, 0); bfr[ni][1] = RDB(ni, 1); }
    if (pf) STAGE_A(t + 2, nb2, 1);
    __builtin_amdgcn_s_barrier();
    asm volatile("s_waitcnt lgkmcnt(0)" ::: "memory");
    __builtin_amdgcn_sched_barrier(0);
    QUAD(0, 1);
    __builtin_amdgcn_s_barrier();

#pragma unroll
    for (int mi = 2; mi < 4; ++mi) { af[mi][0] = RDA(mi, 0); af[mi][1] = RDA(mi, 1); }
    if (pf) STAGE_B(t + 2, nb2);
    __builtin_amdgcn_s_barrier();
    asm volatile("s_waitcnt lgkmcnt(0)" ::: "memory");
    __builtin_amdgcn_sched_barrier(0);
    QUAD(1, 1);
    __builtin_amdgcn_s_barrier();

    QUAD(1, 0);
    if (pf)              asm volatile("s_waitcnt vmcnt(6)" ::: "memory");
    else if (t + 1 < nk) asm volatile("s_waitcnt vmcnt(0)" ::: "memory");
    __builtin_amdgcn_s_barrier();
  }

#pragma unroll
  for (int nt = 0; nt < 4; ++nt) {
    int gn = n0 + wc * 64 + nt * 16 + col;
    float bv = bias[gn];
#pragma unroll
    for (int mt = 0; mt < 4; ++mt) {
      int mbase = m0 + wr * 64 + mt * 16 + g * 4;
#pragma unroll
      for (int r = 0; r < 4; ++r)
        Cout[(size_t)(mbase + r) * N + gn] = acc[mt][nt][r] + bv;
    }
  }
}

// ---------------- fused temporal flash attention (R21 verbatim — best measured) ----------------
__global__ __launch_bounds__(512, 2) void attn_fwd(
    const u16* __restrict__ Qb, const u16* __restrict__ Kb, const u16* __restrict__ Vt,
    const float* __restrict__ Bk, u16* __restrict__ AO)
{
  __shared__ u16 lK[3][64 * 64];     // [key][dh] swz ^(key&7)   24KB
  __shared__ u16 lV[3][64 * 64];     // [d][key]  swz ^(d&7)     24KB => 48KB

  const int phys = blockIdx.x;            // 512 blocks
  const int xcd = phys & 7, s = phys >> 3;
  const int bh = xcd * 8 + (s >> 3);
  const int pr = s & 7;
  const int qa = pr, qbt = 15 - pr;
  const int b = bh >> 4, h = bh & 15;

  const int tid = threadIdx.x, w = tid >> 6, lane = tid & 63;
  const int g = lane >> 4, q16 = lane & 15;

  const float* Bkb = Bk + (size_t)bh * L_;

  int kcol[2], vcol[4];
#pragma unroll
  for (int kk = 0; kk < 2; ++kk) kcol[kk] = ((kk * 4 + g) ^ (q16 & 7)) << 4;
#pragma unroll
  for (int t = 0; t < 4; ++t)
    vcol[t] = (((2 * t + (g >> 1)) ^ (q16 & 7)) << 4) + (g & 1) * 8;

  const int nkA = (qa + 1) * 2;
  const int nkB = (qbt + 1) * 2;

  auto STAGE = [&](int gst, int nb) {
    const int kt = (gst < nkA) ? gst : gst - nkA;
    const int kg0 = kt * 64;
    const int r8 = tid >> 3, cc = tid & 7;
    gload16(Kb + ((size_t)bh * L_ + kg0 + r8) * 64 + ((cc ^ (r8 & 7)) * 8),
            (char*)lK[nb] + tid * 16);
    gload16(Vt + ((size_t)(bh * 64 + r8)) * L_ + kg0 + ((cc ^ (r8 & 7)) * 8),
            (char*)lV[nb] + tid * 16);
  };

  auto QKBODY = [&](bf16x8 (&qf)[2], float& l_r, float mn,
                    int qrow, int kg0, int cur, s16x4 (&pf)[4]) {
    f32x4 sv[4];
#pragma unroll
    for (int t = 0; t < 4; ++t)
      sv[t] = *(const f32x4*)(Bkb + kg0 + t * 16 + g * 4);

    __builtin_amdgcn_s_setprio(1);
#pragma unroll
    for (int t = 0; t < 4; ++t) {
      const char* krow = (const char*)lK[cur] + t * 2048 + q16 * 128;
#pragma unroll
      for (int kk = 0; kk < 2; ++kk) {
        bf16x8 kf = *(const bf16x8*)(krow + kcol[kk]);
        sv[t] = __builtin_amdgcn_mfma_f32_16x16x32_bf16(kf, qf[kk], sv[t], 0, 0, 0);
      }
    }
    __builtin_amdgcn_s_setprio(0);

    if (kg0 + 63 > qrow) {
      const int qg = qrow + q16;
#pragma unroll
      for (int t = 0; t < 4; ++t)
#pragma unroll
        for (int r = 0; r < 4; ++r)
          sv[t][r] = (kg0 + t * 16 + g * 4 + r <= qg) ? sv[t][r] : -INFINITY;
    }

    float rs = 0.f;
#pragma unroll
    for (int t = 0; t < 4; ++t) {
      s16x4 pp;
#pragma unroll
      for (int r = 0; r < 4; ++r) {
        float pv = exp2_fast(sv[t][r] - mn);
        rs += pv;
        pp[r] = (short)f2bf(pv);
      }
      pf[t] = pp;
    }
    l_r += rs;
  };

  auto PVBODY = [&](f32x4 (&o)[4], s16x4 (&pf)[4], int vb) {
    __builtin_amdgcn_s_setprio(1);
#pragma unroll
    for (int t = 0; t < 4; ++t) {
      const char* vrow = (const char*)lV[vb] + q16 * 128 + vcol[t];
#pragma unroll
      for (int db = 0; db < 4; ++db) {
        s16x4 vf = *(const s16x4*)(vrow + db * 2048);
        o[db] = mfma16(vf, pf[t], o[db]);
      }
    }
    __builtin_amdgcn_s_setprio(0);
  };

  auto EPI = [&](f32x4 (&o)[4], float l_r, int qt) {
    float lt = l_r + __shfl_xor(l_r, 16);
    lt += __shfl_xor(lt, 32);
    float inv = 1.f / lt;
    u16* dst = AO + ((size_t)(b * L_ + qt * 128 + w * 16 + q16)) * DM_ + h * 64 + g * 4;
#pragma unroll
    for (int db = 0; db < 4; ++db) {
      u32x2 pk;
      pk[0] = (u32)f2bf(o[db][0] * inv) | ((u32)f2bf(o[db][1] * inv) << 16);
      pk[1] = (u32)f2bf(o[db][2] * inv) | ((u32)f2bf(o[db][3] * inv) << 16);
      *(u32x2*)(dst + db * 16) = pk;
    }
  };

  STAGE(0, 0);
  asm volatile("s_waitcnt vmcnt(0) lgkmcnt(0)" ::: "memory");
  __builtin_amdgcn_s_barrier();
  __builtin_amdgcn_sched_barrier(0);

  // ================= tile A =================
  {
    const int qrow = qa * 128 + w * 16;
    const int mkt = (qrow + 79) >> 6;
    const float mn = Bkb[qrow + q16] + 8.f;
    bf16x8 qf[2];
    {
      const u16* Qr = Qb + ((size_t)bh * L_ + qrow + q16) * 64;
      qf[0] = *(const bf16x8*)(Qr + g * 8);
      qf[1] = *(const bf16x8*)(Qr + 32 + g * 8);
    }
    float l_r = 0.f;
    f32x4 o[4];
#pragma unroll
    for (int db = 0; db < 4; ++db) {
      o[db][0] = 0.f; o[db][1] = 0.f; o[db][2] = 0.f; o[db][3] = 0.f;
    }
    s16x4 pfP[4];
    int pvb = 0;
    bool pvalid = false;
    for (int st = 0; st < nkA; ++st) {
      const int cur = st % 3;
      STAGE(st + 1, (st + 1) % 3);
      const bool doqk = st < mkt;
      s16x4 pfC[4];
      if (doqk) QKBODY(qf, l_r, mn, qrow, st * 64, cur, pfC);
      if (pvalid) PVBODY(o, pfP, pvb);
      if (doqk) {
#pragma unroll
        for (int t = 0; t < 4; ++t) pfP[t] = pfC[t];
        pvb = cur;
      }
      pvalid = doqk;
      asm volatile("s_waitcnt vmcnt(0) lgkmcnt(0)" ::: "memory");
      __builtin_amdgcn_s_barrier();
      __builtin_amdgcn_sched_barrier(0);
    }
    if (pvalid) PVBODY(o, pfP, pvb);
    EPI(o, l_r, qa);
  }
  __builtin_amdgcn_s_barrier();

  // ================= tile B =================
  {
    const int qrow = qbt * 128 + w * 16;
    const int mkt = (qrow + 79) >> 6;
    const float mn = Bkb[qrow + q16] + 8.f;
    bf16x8 qf[2];
    {
      const u16* Qr = Qb + ((size_t)bh * L_ + qrow + q16) * 64;
      qf[0] = *(const bf16x8*)(Qr + g * 8);
      qf[1] = *(const bf16x8*)(Qr + 32 + g * 8);
    }
    float l_r = 0.f;
    f32x4 o[4];
#pragma unroll
    for (int db = 0; db < 4; ++db) {
      o[db][0] = 0.f; o[db][1] = 0.f; o[db][2] = 0.f; o[db][3] = 0.f;
    }
    s16x4 pfP[4];
    int pvb = 0;
    bool pvalid = false;
    for (int kt = 0; kt < nkB; ++kt) {
      const int gst = nkA + kt;
      const int cur = gst % 3;
      if (kt + 1 < nkB) STAGE(gst + 1, (gst + 1) % 3);
      const bool doqk = kt < mkt;
      s16x4 pfC[4];
      if (doqk) QKBODY(qf, l_r, mn, qrow, kt * 64, cur, pfC);
      if (pvalid) PVBODY(o, pfP, pvb);
      if (doqk) {
#pragma unroll
        for (int t = 0; t < 4; ++t) pfP[t] = pfC[t];
        pvb = cur;
      }
      pvalid = doqk;
      if (kt + 1 < nkB) {
        asm volatile("s_waitcnt vmcnt(0) lgkmcnt(0)" ::: "memory");
        __builtin_amdgcn_s_barrier();
        __builtin_amdgcn_sched_barrier(0);
      }
    }
    if (pvalid) PVBODY(o, pfP, pvb);
    EPI(o, l_r, qbt);
  }
}

// ---------------- launcher ----------------
extern "C" void kernel_launch(void* const* d_in, const int* in_sizes, int n_in,
                              void* d_out, int out_size, void* d_ws, size_t ws_size,
                              hipStream_t stream) {
  const float* x    = (const float*)d_in[0];
  const float* ts   = (const float*)d_in[1];
  const float* mk   = (const float*)d_in[2];
  const float* Wqkv = (const float*)d_in[3];
  const float* bqkv = (const float*)d_in[4];
  const float* Wout = (const float*)d_in[5];
  const float* bout = (const float*)d_in[6];
  const float* dec  = (const float*)d_in[7];
  float* out = (float*)d_out;

  char* ws = (char*)d_ws;
  u16* xbf  = (u16*)(ws + 0);
  u16* wqbf = (u16*)(ws + 16777216);
  u16* wobf = (u16*)(ws + 23068672);
  u16* Qb   = (u16*)(ws + 25165824);
  u16* Kb   = (u16*)(ws + 41943040);
  u16* Vt   = (u16*)(ws + 58720256);
  u16* AO   = (u16*)(ws + 75497472);
  float* Bk = (float*)(ws + 92274688);   // 64*2048*4 = 512KB

  // cvt + bias fused: 12288 cvt blocks + 512 bias blocks
  cvt3b<<<dim3((NTOT4 + 64 * 2048) / 256), 256, 0, stream>>>(
      x, Wqkv, Wout, xbf, wqbf, wobf, ts, mk, dec, Bk);

  // QKV GEMM: 256x256 tile, grid = (8192/256)*(3072/256) = 384 blocks
  gemm_qkv<<<dim3(384), 512, 0, stream>>>(xbf, wqbf, bqkv, Qb, Kb, Vt);

  attn_fwd<<<dim3(512), 512, 0, stream>>>(Qb, Kb, Vt, Bk, AO);

  // output GEMM: 256x128 tile, grid = (8192/256)*(1024/128) = 256 blocks
  gemm_bf16<<<dim3(256), 512, 0, stream>>>(
      AO, wobf, bout, 8192, 1024, 1024, 1, nullptr, nullptr, nullptr, out);
}

// Round 17
// 171.322 us; speedup vs baseline: 1.3808x; 1.3808x over previous
//
#include <hip/hip_runtime.h>
#include <stdint.h>
#include <math.h>

#define B_   4
#define L_   2048
#define H_   16
#define DH_  64
#define DM_  1024

typedef __bf16 bf16;
typedef __attribute__((ext_vector_type(8))) __bf16 bf16x8;
typedef __attribute__((ext_vector_type(4))) float f32x4;
typedef __attribute__((ext_vector_type(4))) int i32x4;
typedef __attribute__((ext_vector_type(4))) short s16x4;
typedef unsigned short u16;
typedef unsigned int u32;
typedef __attribute__((ext_vector_type(2))) unsigned int u32x2;
typedef __attribute__((ext_vector_type(4))) unsigned short u16x4;

typedef unsigned int u32g __attribute__((address_space(1)));
typedef unsigned int u32l __attribute__((address_space(3)));

__device__ __forceinline__ u16 f2bf(float f) {
  return __builtin_bit_cast(u16, (bf16)f);   // fptrunc = RNE
}

// 2^x via the HW transcendental unit (scores are kept in log2 units)
__device__ __forceinline__ float exp2_fast(float x) {
  float r; asm("v_exp_f32 %0, %1" : "=v"(r) : "v"(x)); return r;
}

// async global->LDS 16B; LDS dest must be wave-uniform base + lane*16
__device__ __forceinline__ void gload16(const void* g, void* l) {
  __builtin_amdgcn_global_load_lds((const u32g*)g, (u32l*)l, 16, 0, 0);
}

// K=16 bf16 MFMA: A/B are 4 bf16 per lane with k=(lane>>4)*4+j — this matches
// the C-layout of the QK 16x16x32 MFMA, so P needs NO cross-lane transpose.
__device__ __forceinline__ f32x4 mfma16(s16x4 a, s16x4 b, f32x4 c) {
#if __has_builtin(__builtin_amdgcn_mfma_f32_16x16x16bf16_1k)
  return __builtin_amdgcn_mfma_f32_16x16x16bf16_1k(a, b, c, 0, 0, 0);
#else
  asm volatile("v_mfma_f32_16x16x16_bf16 %0, %1, %2, %0\n\ts_nop 7\n\ts_nop 2"
               : "+v"(c) : "v"(a), "v"(b));
  return c;
#endif
}

// ---------------- fused f32 -> bf16 conversion + bias table (one launch) ----------------
#define NX4 2097152                  // 8192*1024/4
#define NQ4 786432                   // 3072*1024/4
#define NO4 262144                   // 1024*1024/4
#define NTOT4 (NX4 + NQ4 + NO4)      // 3145728
__global__ __launch_bounds__(256) void cvt3b(const float* __restrict__ x,
                                             const float* __restrict__ wq,
                                             const float* __restrict__ wo,
                                             u16* __restrict__ xb, u16* __restrict__ wqb,
                                             u16* __restrict__ wob,
                                             const float* __restrict__ ts,
                                             const float* __restrict__ msk,
                                             const float* __restrict__ decay,
                                             float* __restrict__ Bk) {
  int i = blockIdx.x * 256 + threadIdx.x;    // grid = NTOT4 + 64*2048 threads
  if (i >= NTOT4) {
    int j = i - NTOT4;                       // 0 .. 131071
    int bh = j >> 11, l = j & (L_ - 1);
    int b = bh >> 4, h = bh & 15;
    float dc24 = log1pf(__expf(decay[h])) * (1.0f / 24.0f) * 1.44269504f;
    float tv = ts[b * L_ + l], mv = msk[b * L_ + l];
    Bk[j] = (mv != 0.f) ? dc24 * tv : -INFINITY;
    return;
  }
  const float* src; u16* dst; int j;
  if (i < NX4)            { src = x;  dst = xb;  j = i; }
  else if (i < NX4 + NQ4) { src = wq; dst = wqb; j = i - NX4; }
  else                    { src = wo; dst = wob; j = i - NX4 - NQ4; }
  f32x4 v = ((const f32x4*)src)[j];
  u16x4 o;
  o[0] = f2bf(v[0]); o[1] = f2bf(v[1]); o[2] = f2bf(v[2]); o[3] = f2bf(v[3]);
  ((u16x4*)dst)[j] = o;
}

// ---------------- QKV GEMM (R20 verbatim — measured 75us; geometry fixed point) ----------------
// 256x256 tile, BK=64, 512 thr = 2M x 4N waves (128x64/wave), acc[8][4].
// 2 x 64KB LDS buffers; quarter-granular staggered staging; one counted
// vmcnt(6) per K-tile. Constraints established this session:
//  * 8-wave block -> 2 waves/SIMD -> hard 256-reg/wave; this uses ~252.
//    Lookahead reads (+24 regs) spill at any launch_bounds (R22/R23).
//  * B direct-from-global exposes L2 latency per phase (R25: 140us).
//  * LDS-BW model: 192 b128/tile/CU ~ 2300cyc vs 640cyc MFMA -> ~28%
//    MfmaUtil ceiling; measured 26.4%. This is the structure's floor.
__global__ __launch_bounds__(512) void gemm_qkv(
    const u16* __restrict__ A, const u16* __restrict__ Bm, const float* __restrict__ bias,
    u16* __restrict__ Qb, u16* __restrict__ Kb, u16* __restrict__ Vt)
{
  __shared__ char smem[135168];     // 2 x (A 32KB + B 32KB) = 128KB; epi ltr[256][264]
  u16* ltr = (u16*)smem;
  const int K = 1024, nk = 16;

  const int tid = threadIdx.x;
  const int nwg = gridDim.x;              // 384, %8==0
  int idx = blockIdx.x;
  idx = (idx & 7) * (nwg >> 3) + (idx >> 3);
  const int nbx = 12;                     // N=3072 / 256
  const int bx = idx % nbx, by = idx / nbx;
  const int m0 = by << 8, n0 = bx << 8;

  const int lane = tid & 63, w = tid >> 6;
  const int g = lane >> 4, col = lane & 15;
  const int wr = w >> 2, wc = w & 3;      // 2M x 4N; per-wave C = 128 x 64

  f32x4 acc[8][4];
#pragma unroll
  for (int mt = 0; mt < 8; ++mt)
#pragma unroll
    for (int nt = 0; nt < 4; ++nt) {
      acc[mt][nt][0] = 0.f; acc[mt][nt][1] = 0.f;
      acc[mt][nt][2] = 0.f; acc[mt][nt][3] = 0.f;
    }

  auto SA = [&](int kt, int nb, int q) {
    char* dA = smem + (nb << 16);
    int c = (q << 9) + tid;
    int row = c >> 3, cc = c & 7;
    gload16(A + (size_t)(m0 + row) * K + (kt << 6) + ((cc ^ (row & 7)) << 3), dA + c * 16);
  };
  auto SB = [&](int kt, int nb, int q) {
    char* dB = smem + (nb << 16) + 32768;
    int c = (q << 9) + tid;
    int row = c >> 3, cc = c & 7;
    gload16(Bm + (size_t)(n0 + row) * K + (kt << 6) + ((cc ^ (row & 7)) << 3), dB + c * 16);
  };

  SA(0, 0, 0); SA(0, 0, 1); SA(0, 0, 2); SA(0, 0, 3);
  SB(0, 0, 0); SB(0, 0, 1); SB(0, 0, 2); SB(0, 0, 3);
  SA(1, 1, 0); SA(1, 1, 2); SB(1, 1, 0); SB(1, 1, 1); SA(1, 1, 1); SA(1, 1, 3);
  asm volatile("s_waitcnt vmcnt(6)" ::: "memory");   // tile 0 landed
  __builtin_amdgcn_s_barrier();

  for (int t = 0; t < nk; ++t) {
    const char* bufA = smem + ((t & 1) << 16);
    const char* bufB = bufA + 32768;
    const int nbN = (t + 1) & 1;

    auto RDA = [&](int mt, int kk) {
      int row = wr * 128 + mt * 16 + col;
      return *(const bf16x8*)(bufA + row * 128 + ((((kk << 2) + g) ^ (row & 7)) << 4));
    };
    auto RDB = [&](int nt, int kk) {
      int row = wc * 64 + nt * 16 + col;
      return *(const bf16x8*)(bufB + row * 128 + ((((kk << 2) + g) ^ (row & 7)) << 4));
    };

    bf16x8 af[4][2], bfr[4][2];

    // ---- P1: (m-lo, n-lo) ----
#pragma unroll
    for (int mi = 0; mi < 4; ++mi) { af[mi][0] = RDA(mi, 0); af[mi][1] = RDA(mi, 1); }
#pragma unroll
    for (int ni = 0; ni < 2; ++ni) { bfr[ni][0] = RDB(ni, 0); bfr[ni][1] = RDB(ni, 1); }
    if (t + 1 < nk) { SB(t + 1, nbN, 2); SB(t + 1, nbN, 3); }
    __builtin_amdgcn_s_barrier();
    asm volatile("s_waitcnt lgkmcnt(0)" ::: "memory");
    __builtin_amdgcn_sched_barrier(0);
    __builtin_amdgcn_s_setprio(1);
#pragma unroll
    for (int mi = 0; mi < 4; ++mi)
#pragma unroll
      for (int ni = 0; ni < 2; ++ni)
#pragma unroll
        for (int kk = 0; kk < 2; ++kk)
          acc[mi][ni] = __builtin_amdgcn_mfma_f32_16x16x32_bf16(af[mi][kk], bfr[ni][kk], acc[mi][ni], 0, 0, 0);
    __builtin_amdgcn_s_setprio(0);
    __builtin_amdgcn_s_barrier();

    // ---- P2: (m-lo, n-hi) ----
#pragma unroll
    for (int ni = 2; ni < 4; ++ni) { bfr[ni][0] = RDB(ni, 0); bfr[ni][1] = RDB(ni, 1); }
    if (t + 2 < nk) { SA(t + 2, t & 1, 0); SA(t + 2, t & 1, 2); }
    __builtin_amdgcn_s_barrier();
    asm volatile("s_waitcnt lgkmcnt(0)" ::: "memory");
    __builtin_amdgcn_sched_barrier(0);
    __builtin_amdgcn_s_setprio(1);
#pragma unroll
    for (int mi = 0; mi < 4; ++mi)
#pragma unroll
      for (int ni = 2; ni < 4; ++ni)
#pragma unroll
        for (int kk = 0; kk < 2; ++kk)
          acc[mi][ni] = __builtin_amdgcn_mfma_f32_16x16x32_bf16(af[mi][kk], bfr[ni][kk], acc[mi][ni], 0, 0, 0);
    __builtin_amdgcn_s_setprio(0);
    __builtin_amdgcn_s_barrier();

    // ---- P3: (m-hi, n-hi) — af[] reused for rows mt+4 ----
#pragma unroll
    for (int mi = 0; mi < 4; ++mi) { af[mi][0] = RDA(mi + 4, 0); af[mi][1] = RDA(mi + 4, 1); }
    if (t + 2 < nk) { SB(t + 2, t & 1, 0); SB(t + 2, t & 1, 1); }
    __builtin_amdgcn_s_barrier();
    asm volatile("s_waitcnt lgkmcnt(0)" ::: "memory");
    __builtin_amdgcn_sched_barrier(0);
    __builtin_amdgcn_s_setprio(1);
#pragma unroll
    for (int mi = 0; mi < 4; ++mi)
#pragma unroll
      for (int ni = 2; ni < 4; ++ni)
#pragma unroll
        for (int kk = 0; kk < 2; ++kk)
          acc[mi + 4][ni] = __builtin_amdgcn_mfma_f32_16x16x32_bf16(af[mi][kk], bfr[ni][kk], acc[mi + 4][ni], 0, 0, 0);
    __builtin_amdgcn_s_setprio(0);
    __builtin_amdgcn_s_barrier();

    // ---- P4: (m-hi, n-lo) — pure MFMA; stage; counted wait ----
    if (t + 2 < nk) { SA(t + 2, t & 1, 1); SA(t + 2, t & 1, 3); }
    __builtin_amdgcn_s_setprio(1);
#pragma unroll
    for (int mi = 0; mi < 4; ++mi)
#pragma unroll
      for (int ni = 0; ni < 2; ++ni)
#pragma unroll
        for (int kk = 0; kk < 2; ++kk)
          acc[mi + 4][ni] = __builtin_amdgcn_mfma_f32_16x16x32_bf16(af[mi][kk], bfr[ni][kk], acc[mi + 4][ni], 0, 0, 0);
    __builtin_amdgcn_s_setprio(0);
    if (t + 2 < nk) asm volatile("s_waitcnt vmcnt(6)" ::: "memory");  // t+1 fully landed
    else            asm volatile("s_waitcnt vmcnt(0)" ::: "memory");
    __builtin_amdgcn_s_barrier();
  }

  // ---- mode-0 epilogue via padded LDS transpose: ltr[256][264] u16 ----
  const int type = n0 >> 10;
  const float qsc = (type == 0) ? 0.125f * 1.44269504f : 1.0f;
#pragma unroll
  for (int nt = 0; nt < 4; ++nt) {
    int nn = wc * 64 + nt * 16 + col;
    float bv = bias[n0 + nn];
#pragma unroll
    for (int mt = 0; mt < 8; ++mt) {
      int mm = wr * 128 + mt * 16 + g * 4;
#pragma unroll
      for (int r = 0; r < 4; ++r) {
        u16 hv = f2bf((acc[mt][nt][r] + bv) * qsc);
        if (type < 2) ltr[(mm + r) * 264 + nn] = hv;
        else          ltr[nn * 264 + (mm + r)] = hv;
      }
    }
  }
  __syncthreads();
  if (type < 2) {
#pragma unroll
    for (int it = 0; it < 16; ++it) {
      int cid = tid + it * 512;
      int rrow = cid >> 5, cc = cid & 31;
      i32x4 v = *(const i32x4*)((const char*)ltr + rrow * 528 + cc * 16);
      int token = m0 + rrow;
      int bb = token >> 11, ll = token & (L_ - 1);
      int gn = n0 + cc * 8;
      int head = (gn & 1023) >> 6, d = gn & 63;
      u16* dst = (type == 0) ? Qb : Kb;
      *(i32x4*)(dst + ((size_t)((bb * H_ + head) * L_ + ll)) * 64 + d) = v;
    }
  } else {
#pragma unroll
    for (int it = 0; it < 16; ++it) {
      int cid = tid + it * 512;
      int rrow = cid >> 5, cc = cid & 31;
      i32x4 v = *(const i32x4*)((const char*)ltr + rrow * 528 + cc * 16);
      int gn = n0 + rrow;
      int head = (gn & 1023) >> 6, d = gn & 63;
      int token0 = m0 + cc * 8;
      int bb = token0 >> 11, ll = token0 & (L_ - 1);
      *(i32x4*)(Vt + ((size_t)((bb * H_ + head) * DH_ + d)) * L_ + ll) = v;
    }
  }
}

// ---------------- bf16 GEMM (R17 verbatim — mode-1 output GEMM) ----------------
__global__ __launch_bounds__(512) void gemm_bf16(
    const u16* __restrict__ A, const u16* __restrict__ Bm, const float* __restrict__ bias,
    int M, int N, int K, int mode,
    u16* __restrict__ Qb, u16* __restrict__ Kb, u16* __restrict__ Vt, float* __restrict__ Cout)
{
  __shared__ char smem[147456];
  const int tid = threadIdx.x;
  const int nwg = gridDim.x;
  int idx = blockIdx.x;
  idx = (idx & 7) * (nwg >> 3) + (idx >> 3);
  const int nbx = N >> 7;
  const int bx = idx % nbx, by = idx / nbx;
  const int m0 = by << 8, n0 = bx << 7;

  const int lane = tid & 63, w = tid >> 6;
  const int g = lane >> 4, col = lane & 15;
  const int wr = w >> 1, wc = w & 1;

  f32x4 acc[4][4];
#pragma unroll
  for (int mt = 0; mt < 4; ++mt)
#pragma unroll
    for (int nt = 0; nt < 4; ++nt) {
      acc[mt][nt][0] = 0.f; acc[mt][nt][1] = 0.f;
      acc[mt][nt][2] = 0.f; acc[mt][nt][3] = 0.f;
    }

  auto STAGE_A = [&](int kt, int nb, int hh) {
    char* dA = smem + nb * 49152;
    const int k0 = kt << 6;
#pragma unroll
    for (int pp = hh * 2; pp < hh * 2 + 2; ++pp) {
      int c = tid + pp * 512;
      int row = c >> 3, cc = c & 7;
      gload16(A + (size_t)(m0 + row) * K + k0 + ((cc ^ (row & 7)) << 3), dA + c * 16);
    }
  };
  auto STAGE_B = [&](int kt, int nb) {
    char* dB = smem + nb * 49152 + 32768;
    const int k0 = kt << 6;
#pragma unroll
    for (int pp = 0; pp < 2; ++pp) {
      int c = tid + pp * 512;
      int row = c >> 3, cc = c & 7;
      gload16(Bm + (size_t)(n0 + row) * K + k0 + ((cc ^ (row & 7)) << 3), dB + c * 16);
    }
  };

  STAGE_A(0, 0, 0); STAGE_A(0, 0, 1); STAGE_B(0, 0);
  STAGE_A(1, 1, 0); STAGE_A(1, 1, 1); STAGE_B(1, 1);
  asm volatile("s_waitcnt vmcnt(6)" ::: "memory");
  __builtin_amdgcn_s_barrier();

  const int nk = K >> 6;
  for (int t = 0; t < nk; ++t) {
    const char* bufA = smem + (t % 3) * 49152;
    const char* bufB = bufA + 32768;
    const bool pf = (t + 2 < nk);
    const int nb2 = (t + 2) % 3;

    bf16x8 af[4][2], bfr[4][2];
    auto RDA = [&](int mt, int kk) {
      int row = wr * 64 + mt * 16 + col;
      return *(const bf16x8*)(bufA + row * 128 + ((((kk << 2) + g) ^ (row & 7)) << 4));
    };
    auto RDB = [&](int nt, int kk) {
      int row = wc * 64 + nt * 16 + col;
      return *(const bf16x8*)(bufB + row * 128 + ((((kk << 2) + g) ^ (row & 7)) << 4));
    };
    auto QUAD = [&](int qm, int qn) {
      __builtin_amdgcn_s_setprio(1);
#pragma unroll
      for (int mi = 0; mi < 2; ++mi)
#pragma unroll
        for (int ni = 0; ni < 2; ++ni)
#pragma unroll
          for (int kk = 0; kk < 2; ++kk)
            acc[qm * 2 + mi][qn * 2 + ni] = __builtin_amdgcn_mfma_f32_16x16x32_bf16(
                af[qm * 2 + mi][kk], bfr[qn * 2 + ni][kk], acc[qm * 2 + mi][qn * 2 + ni], 0, 0, 0);
      __builtin_amdgcn_s_setprio(0);
    };

#pragma unroll
    for (int mi = 0; mi < 2; ++mi) { af[mi][0] = RDA(mi, 0); af[mi][1] = RDA(mi, 1); }
#pragma unroll
    for (int ni = 0; ni < 2; ++ni) { bfr[ni][0] = RDB(ni, 0); bfr[ni][1] = RDB(ni, 1); }
    if (pf) STAGE_A(t + 2, nb2, 0);
    __builtin_amdgcn_s_barrier();
    asm volatile("s_waitcnt lgkmcnt(0)" ::: "memory");
    __builtin_amdgcn_sched_barrier(0);
    QUAD(0, 0);
    __builtin_amdgcn_s_barrier();

#pragma unroll
    for (int ni = 2; ni < 4; ++ni) { bfr[ni][0] = RDB(ni, 0); bfr[ni][1] = RDB(ni, 1); }
    if (pf) STAGE_A(t + 2, nb2, 1);
    __builtin_amdgcn_s_barrier();
    asm volatile("s_waitcnt lgkmcnt(0)" ::: "memory");
    __builtin_amdgcn_sched_barrier(0);
    QUAD(0, 1);
    __builtin_amdgcn_s_barrier();

#pragma unroll
    for (int mi = 2; mi < 4; ++mi) { af[mi][0] = RDA(mi, 0); af[mi][1] = RDA(mi, 1); }
    if (pf) STAGE_B(t + 2, nb2);
    __builtin_amdgcn_s_barrier();
    asm volatile("s_waitcnt lgkmcnt(0)" ::: "memory");
    __builtin_amdgcn_sched_barrier(0);
    QUAD(1, 1);
    __builtin_amdgcn_s_barrier();

    QUAD(1, 0);
    if (pf)              asm volatile("s_waitcnt vmcnt(6)" ::: "memory");
    else if (t + 1 < nk) asm volatile("s_waitcnt vmcnt(0)" ::: "memory");
    __builtin_amdgcn_s_barrier();
  }

#pragma unroll
  for (int nt = 0; nt < 4; ++nt) {
    int gn = n0 + wc * 64 + nt * 16 + col;
    float bv = bias[gn];
#pragma unroll
    for (int mt = 0; mt < 4; ++mt) {
      int mbase = m0 + wr * 64 + mt * 16 + g * 4;
#pragma unroll
      for (int r = 0; r < 4; ++r)
        Cout[(size_t)(mbase + r) * N + gn] = acc[mt][nt][r] + bv;
    }
  }
}

// ---------------- fused temporal flash attention (R21 verbatim — best measured) ----------------
__global__ __launch_bounds__(512, 2) void attn_fwd(
    const u16* __restrict__ Qb, const u16* __restrict__ Kb, const u16* __restrict__ Vt,
    const float* __restrict__ Bk, u16* __restrict__ AO)
{
  __shared__ u16 lK[3][64 * 64];     // [key][dh] swz ^(key&7)   24KB
  __shared__ u16 lV[3][64 * 64];     // [d][key]  swz ^(d&7)     24KB => 48KB

  const int phys = blockIdx.x;            // 512 blocks
  const int xcd = phys & 7, s = phys >> 3;
  const int bh = xcd * 8 + (s >> 3);
  const int pr = s & 7;
  const int qa = pr, qbt = 15 - pr;
  const int b = bh >> 4, h = bh & 15;

  const int tid = threadIdx.x, w = tid >> 6, lane = tid & 63;
  const int g = lane >> 4, q16 = lane & 15;

  const float* Bkb = Bk + (size_t)bh * L_;

  int kcol[2], vcol[4];
#pragma unroll
  for (int kk = 0; kk < 2; ++kk) kcol[kk] = ((kk * 4 + g) ^ (q16 & 7)) << 4;
#pragma unroll
  for (int t = 0; t < 4; ++t)
    vcol[t] = (((2 * t + (g >> 1)) ^ (q16 & 7)) << 4) + (g & 1) * 8;

  const int nkA = (qa + 1) * 2;
  const int nkB = (qbt + 1) * 2;

  auto STAGE = [&](int gst, int nb) {
    const int kt = (gst < nkA) ? gst : gst - nkA;
    const int kg0 = kt * 64;
    const int r8 = tid >> 3, cc = tid & 7;
    gload16(Kb + ((size_t)bh * L_ + kg0 + r8) * 64 + ((cc ^ (r8 & 7)) * 8),
            (char*)lK[nb] + tid * 16);
    gload16(Vt + ((size_t)(bh * 64 + r8)) * L_ + kg0 + ((cc ^ (r8 & 7)) * 8),
            (char*)lV[nb] + tid * 16);
  };

  auto QKBODY = [&](bf16x8 (&qf)[2], float& l_r, float mn,
                    int qrow, int kg0, int cur, s16x4 (&pf)[4]) {
    f32x4 sv[4];
#pragma unroll
    for (int t = 0; t < 4; ++t)
      sv[t] = *(const f32x4*)(Bkb + kg0 + t * 16 + g * 4);

    __builtin_amdgcn_s_setprio(1);
#pragma unroll
    for (int t = 0; t < 4; ++t) {
      const char* krow = (const char*)lK[cur] + t * 2048 + q16 * 128;
#pragma unroll
      for (int kk = 0; kk < 2; ++kk) {
        bf16x8 kf = *(const bf16x8*)(krow + kcol[kk]);
        sv[t] = __builtin_amdgcn_mfma_f32_16x16x32_bf16(kf, qf[kk], sv[t], 0, 0, 0);
      }
    }
    __builtin_amdgcn_s_setprio(0);

    if (kg0 + 63 > qrow) {
      const int qg = qrow + q16;
#pragma unroll
      for (int t = 0; t < 4; ++t)
#pragma unroll
        for (int r = 0; r < 4; ++r)
          sv[t][r] = (kg0 + t * 16 + g * 4 + r <= qg) ? sv[t][r] : -INFINITY;
    }

    float rs = 0.f;
#pragma unroll
    for (int t = 0; t < 4; ++t) {
      s16x4 pp;
#pragma unroll
      for (int r = 0; r < 4; ++r) {
        float pv = exp2_fast(sv[t][r] - mn);
        rs += pv;
        pp[r] = (short)f2bf(pv);
      }
      pf[t] = pp;
    }
    l_r += rs;
  };

  auto PVBODY = [&](f32x4 (&o)[4], s16x4 (&pf)[4], int vb) {
    __builtin_amdgcn_s_setprio(1);
#pragma unroll
    for (int t = 0; t < 4; ++t) {
      const char* vrow = (const char*)lV[vb] + q16 * 128 + vcol[t];
#pragma unroll
      for (int db = 0; db < 4; ++db) {
        s16x4 vf = *(const s16x4*)(vrow + db * 2048);
        o[db] = mfma16(vf, pf[t], o[db]);
      }
    }
    __builtin_amdgcn_s_setprio(0);
  };

  auto EPI = [&](f32x4 (&o)[4], float l_r, int qt) {
    float lt = l_r + __shfl_xor(l_r, 16);
    lt += __shfl_xor(lt, 32);
    float inv = 1.f / lt;
    u16* dst = AO + ((size_t)(b * L_ + qt * 128 + w * 16 + q16)) * DM_ + h * 64 + g * 4;
#pragma unroll
    for (int db = 0; db < 4; ++db) {
      u32x2 pk;
      pk[0] = (u32)f2bf(o[db][0] * inv) | ((u32)f2bf(o[db][1] * inv) << 16);
      pk[1] = (u32)f2bf(o[db][2] * inv) | ((u32)f2bf(o[db][3] * inv) << 16);
      *(u32x2*)(dst + db * 16) = pk;
    }
  };

  STAGE(0, 0);
  asm volatile("s_waitcnt vmcnt(0) lgkmcnt(0)" ::: "memory");
  __builtin_amdgcn_s_barrier();
  __builtin_amdgcn_sched_barrier(0);

  // ================= tile A =================
  {
    const int qrow = qa * 128 + w * 16;
    const int mkt = (qrow + 79) >> 6;
    const float mn = Bkb[qrow + q16] + 8.f;
    bf16x8 qf[2];
    {
      const u16* Qr = Qb + ((size_t)bh * L_ + qrow + q16) * 64;
      qf[0] = *(const bf16x8*)(Qr + g * 8);
      qf[1] = *(const bf16x8*)(Qr + 32 + g * 8);
    }
    float l_r = 0.f;
    f32x4 o[4];
#pragma unroll
    for (int db = 0; db < 4; ++db) {
      o[db][0] = 0.f; o[db][1] = 0.f; o[db][2] = 0.f; o[db][3] = 0.f;
    }
    s16x4 pfP[4];
    int pvb = 0;
    bool pvalid = false;
    for (int st = 0; st < nkA; ++st) {
      const int cur = st % 3;
      STAGE(st + 1, (st + 1) % 3);
      const bool doqk = st < mkt;
      s16x4 pfC[4];
      if (doqk) QKBODY(qf, l_r, mn, qrow, st * 64, cur, pfC);
      if (pvalid) PVBODY(o, pfP, pvb);
      if (doqk) {
#pragma unroll
        for (int t = 0; t < 4; ++t) pfP[t] = pfC[t];
        pvb = cur;
      }
      pvalid = doqk;
      asm volatile("s_waitcnt vmcnt(0) lgkmcnt(0)" ::: "memory");
      __builtin_amdgcn_s_barrier();
      __builtin_amdgcn_sched_barrier(0);
    }
    if (pvalid) PVBODY(o, pfP, pvb);
    EPI(o, l_r, qa);
  }
  __builtin_amdgcn_s_barrier();

  // ================= tile B =================
  {
    const int qrow = qbt * 128 + w * 16;
    const int mkt = (qrow + 79) >> 6;
    const float mn = Bkb[qrow + q16] + 8.f;
    bf16x8 qf[2];
    {
      const u16* Qr = Qb + ((size_t)bh * L_ + qrow + q16) * 64;
      qf[0] = *(const bf16x8*)(Qr + g * 8);
      qf[1] = *(const bf16x8*)(Qr + 32 + g * 8);
    }
    float l_r = 0.f;
    f32x4 o[4];
#pragma unroll
    for (int db = 0; db < 4; ++db) {
      o[db][0] = 0.f; o[db][1] = 0.f; o[db][2] = 0.f; o[db][3] = 0.f;
    }
    s16x4 pfP[4];
    int pvb = 0;
    bool pvalid = false;
    for (int kt = 0; kt < nkB; ++kt) {
      const int gst = nkA + kt;
      const int cur = gst % 3;
      if (kt + 1 < nkB) STAGE(gst + 1, (gst + 1) % 3);
      const bool doqk = kt < mkt;
      s16x4 pfC[4];
      if (doqk) QKBODY(qf, l_r, mn, qrow, kt * 64, cur, pfC);
      if (pvalid) PVBODY(o, pfP, pvb);
      if (doqk) {
#pragma unroll
        for (int t = 0; t < 4; ++t) pfP[t] = pfC[t];
        pvb = cur;
      }
      pvalid = doqk;
      if (kt + 1 < nkB) {
        asm volatile("s_waitcnt vmcnt(0) lgkmcnt(0)" ::: "memory");
        __builtin_amdgcn_s_barrier();
        __builtin_amdgcn_sched_barrier(0);
      }
    }
    if (pvalid) PVBODY(o, pfP, pvb);
    EPI(o, l_r, qbt);
  }
}

// ---------------- launcher ----------------
extern "C" void kernel_launch(void* const* d_in, const int* in_sizes, int n_in,
                              void* d_out, int out_size, void* d_ws, size_t ws_size,
                              hipStream_t stream) {
  const float* x    = (const float*)d_in[0];
  const float* ts   = (const float*)d_in[1];
  const float* mk   = (const float*)d_in[2];
  const float* Wqkv = (const float*)d_in[3];
  const float* bqkv = (const float*)d_in[4];
  const float* Wout = (const float*)d_in[5];
  const float* bout = (const float*)d_in[6];
  const float* dec  = (const float*)d_in[7];
  float* out = (float*)d_out;

  char* ws = (char*)d_ws;
  u16* xbf  = (u16*)(ws + 0);
  u16* wqbf = (u16*)(ws + 16777216);
  u16* wobf = (u16*)(ws + 23068672);
  u16* Qb   = (u16*)(ws + 25165824);
  u16* Kb   = (u16*)(ws + 41943040);
  u16* Vt   = (u16*)(ws + 58720256);
  u16* AO   = (u16*)(ws + 75497472);
  float* Bk = (float*)(ws + 92274688);   // 64*2048*4 = 512KB

  // cvt + bias fused: 12288 cvt blocks + 512 bias blocks
  cvt3b<<<dim3((NTOT4 + 64 * 2048) / 256), 256, 0, stream>>>(
      x, Wqkv, Wout, xbf, wqbf, wobf, ts, mk, dec, Bk);

  // QKV GEMM: 256x256 tile, grid = (8192/256)*(3072/256) = 384 blocks
  gemm_qkv<<<dim3(384), 512, 0, stream>>>(xbf, wqbf, bqkv, Qb, Kb, Vt);

  attn_fwd<<<dim3(512), 512, 0, stream>>>(Qb, Kb, Vt, Bk, AO);

  // output GEMM: 256x128 tile, grid = (8192/256)*(1024/128) = 256 blocks
  gemm_bf16<<<dim3(256), 512, 0, stream>>>(
      AO, wobf, bout, 8192, 1024, 1024, 1, nullptr, nullptr, nullptr, out);
}

// Round 18
// 167.333 us; speedup vs baseline: 1.4137x; 1.0238x over previous
//
#include <hip/hip_runtime.h>
#include <stdint.h>
#include <math.h>

#define B_   4
#define L_   2048
#define H_   16
#define DH_  64
#define DM_  1024

typedef __bf16 bf16;
typedef __attribute__((ext_vector_type(8))) __bf16 bf16x8;
typedef __attribute__((ext_vector_type(4))) float f32x4;
typedef __attribute__((ext_vector_type(4))) int i32x4;
typedef __attribute__((ext_vector_type(4))) short s16x4;
typedef unsigned short u16;
typedef unsigned int u32;
typedef __attribute__((ext_vector_type(2))) unsigned int u32x2;
typedef __attribute__((ext_vector_type(4))) unsigned short u16x4;

typedef unsigned int u32g __attribute__((address_space(1)));
typedef unsigned int u32l __attribute__((address_space(3)));

__device__ __forceinline__ u16 f2bf(float f) {
  return __builtin_bit_cast(u16, (bf16)f);   // fptrunc = RNE
}

// 2^x via the HW transcendental unit (scores are kept in log2 units)
__device__ __forceinline__ float exp2_fast(float x) {
  float r; asm("v_exp_f32 %0, %1" : "=v"(r) : "v"(x)); return r;
}

// async global->LDS 16B; LDS dest must be wave-uniform base + lane*16
__device__ __forceinline__ void gload16(const void* g, void* l) {
  __builtin_amdgcn_global_load_lds((const u32g*)g, (u32l*)l, 16, 0, 0);
}

// K=16 bf16 MFMA: A/B are 4 bf16 per lane with k=(lane>>4)*4+j — this matches
// the C-layout of the QK 16x16x32 MFMA, so P needs NO cross-lane transpose.
__device__ __forceinline__ f32x4 mfma16(s16x4 a, s16x4 b, f32x4 c) {
#if __has_builtin(__builtin_amdgcn_mfma_f32_16x16x16bf16_1k)
  return __builtin_amdgcn_mfma_f32_16x16x16bf16_1k(a, b, c, 0, 0, 0);
#else
  asm volatile("v_mfma_f32_16x16x16_bf16 %0, %1, %2, %0\n\ts_nop 7\n\ts_nop 2"
               : "+v"(c) : "v"(a), "v"(b));
  return c;
#endif
}

// ---------------- fused f32 -> bf16 conversion + bias table (one launch) ----------------
#define NX4 2097152                  // 8192*1024/4
#define NQ4 786432                   // 3072*1024/4
#define NO4 262144                   // 1024*1024/4
#define NTOT4 (NX4 + NQ4 + NO4)      // 3145728
__global__ __launch_bounds__(256) void cvt3b(const float* __restrict__ x,
                                             const float* __restrict__ wq,
                                             const float* __restrict__ wo,
                                             u16* __restrict__ xb, u16* __restrict__ wqb,
                                             u16* __restrict__ wob,
                                             const float* __restrict__ ts,
                                             const float* __restrict__ msk,
                                             const float* __restrict__ decay,
                                             float* __restrict__ Bk) {
  int i = blockIdx.x * 256 + threadIdx.x;    // grid = NTOT4 + 64*2048 threads
  if (i >= NTOT4) {
    int j = i - NTOT4;                       // 0 .. 131071
    int bh = j >> 11, l = j & (L_ - 1);
    int b = bh >> 4, h = bh & 15;
    float dc24 = log1pf(__expf(decay[h])) * (1.0f / 24.0f) * 1.44269504f;
    float tv = ts[b * L_ + l], mv = msk[b * L_ + l];
    Bk[j] = (mv != 0.f) ? dc24 * tv : -INFINITY;
    return;
  }
  const float* src; u16* dst; int j;
  if (i < NX4)            { src = x;  dst = xb;  j = i; }
  else if (i < NX4 + NQ4) { src = wq; dst = wqb; j = i - NX4; }
  else                    { src = wo; dst = wob; j = i - NX4 - NQ4; }
  f32x4 v = ((const f32x4*)src)[j];
  u16x4 o;
  o[0] = f2bf(v[0]); o[1] = f2bf(v[1]); o[2] = f2bf(v[2]); o[3] = f2bf(v[3]);
  ((u16x4*)dst)[j] = o;
}

// ---------------- QKV GEMM R27: 256x192 tile -> 512 blocks = 2 EXACT rounds ----------------
// Grid-quantization model (validated twice: R20 75.0us = 2x37.5 at 1.5 rounds;
// R17-GEMM1 76us = equal effective cost 1.333): effective ~ LDS-reads/util.
// 256x192 (wave 128x48, 2Mx4N): reads/tile 176KB (vs 192), util 1.0 (vs .75)
// -> relative 1.222/1.333 = 0.917 -> ~69us predicted.
// Schedule = R20's proven 4-phase depth-2 stagger with B in 3 chunks:
//   loads/tile = 7 (A q0..q3 + B c0..c2); staging: SB(t+1,c1,c2)@P1,
//   SA(t+2,q0,q2)@P2, SB(t+2,c0)@P3, SA(t+2,q1,q3)@P4; counted vmcnt(5)@P4
//   (leaves t+2's 5 newest; forces t+1's 7 complete). Region safety as R20:
//   A q0/q2 dead after P1 lgkm0, q1/q3 after P3; B fully read by P2 end.
// Phases: P1 m-lo x n{0,1} (16 MFMA) | P2 m-lo x n{2} (8) | P3 m-hi x n{2}
//   (8, reads af-hi) | P4 m-hi x n{0,1} (16, all operands live).
// Epilogue: 192-tiles cross Q/K (1024) and K/V (2048) boundaries -> two
//   uniform-branch passes: pass1 Q/K (layout1, per-element dst+scale),
//   pass2 V (transpose layout2). Only tile n0=1920 runs both.
__global__ __launch_bounds__(512) void gemm_qkv(
    const u16* __restrict__ A, const u16* __restrict__ Bm, const float* __restrict__ bias,
    u16* __restrict__ Qb, u16* __restrict__ Kb, u16* __restrict__ Vt)
{
  __shared__ char smem[114688];   // A0,A1 32KB @0,32768; B0,B1 24KB @65536,90112
  u16* ltr = (u16*)smem;          // epi: pass1 [256][200] 100KB, pass2 [192][264] 99KB
  const int K = 1024, nk = 16;

  const int tid = threadIdx.x;
  const int nwg = gridDim.x;              // 512, %8==0
  int idx = blockIdx.x;
  idx = (idx & 7) * (nwg >> 3) + (idx >> 3);
  const int nbx = 16;                     // N=3072 / 192
  const int bx = idx % nbx, by = idx / nbx;
  const int m0 = by << 8, n0 = bx * 192;

  const int lane = tid & 63, w = tid >> 6;
  const int g = lane >> 4, col = lane & 15;
  const int wr = w >> 2, wc = w & 3;      // 2M x 4N; per-wave C = 128 x 48

  f32x4 acc[8][3];
#pragma unroll
  for (int mt = 0; mt < 8; ++mt)
#pragma unroll
    for (int nt = 0; nt < 3; ++nt) {
      acc[mt][nt][0] = 0.f; acc[mt][nt][1] = 0.f;
      acc[mt][nt][2] = 0.f; acc[mt][nt][3] = 0.f;
    }

  // stage A quarter q (rows q*64..+63) of tile kt into buf nb — 1 load/thread
  auto SA = [&](int kt, int nb, int q) {
    char* dA = smem + nb * 32768;
    int c = (q << 9) + tid;
    int row = c >> 3, cc = c & 7;
    gload16(A + (size_t)(m0 + row) * K + (kt << 6) + ((cc ^ (row & 7)) << 3), dA + c * 16);
  };
  // stage B chunk q (rows q*64..+63, 192 rows total) — 1 load/thread
  auto SB = [&](int kt, int nb, int q) {
    char* dB = smem + 65536 + nb * 24576;
    int c = (q << 9) + tid;
    int row = c >> 3, cc = c & 7;
    gload16(Bm + (size_t)(n0 + row) * K + (kt << 6) + ((cc ^ (row & 7)) << 3), dB + c * 16);
  };

  auto RDA = [&](const char* bA, int mt, int kk) {
    int row = wr * 128 + mt * 16 + col;
    return *(const bf16x8*)(bA + row * 128 + ((((kk << 2) + g) ^ (row & 7)) << 4));
  };
  auto RDB = [&](const char* bB, int nt, int kk) {
    int row = wc * 48 + nt * 16 + col;
    return *(const bf16x8*)(bB + row * 128 + ((((kk << 2) + g) ^ (row & 7)) << 4));
  };

  // ---- prologue: t0 full (7) + t1 partial (5; B c1,c2 deferred to t0.P1) ----
  SA(0, 0, 0); SA(0, 0, 1); SA(0, 0, 2); SA(0, 0, 3);
  SB(0, 0, 0); SB(0, 0, 1); SB(0, 0, 2);
  SA(1, 1, 0); SA(1, 1, 1); SA(1, 1, 2); SA(1, 1, 3);
  SB(1, 1, 0);
  asm volatile("s_waitcnt vmcnt(5)" ::: "memory");   // t0's 7 landed; t1's 5 in flight
  __builtin_amdgcn_s_barrier();

  for (int t = 0; t < nk; ++t) {
    const char* bufA = smem + (t & 1) * 32768;
    const char* bufB = smem + 65536 + (t & 1) * 24576;
    const int nbN = (t + 1) & 1;
    const int nbC = t & 1;               // buffer of tile t+2

    bf16x8 af[4][2], bf[3][2];

    // ---- P1: m-lo x n{0,1} ----
#pragma unroll
    for (int mi = 0; mi < 4; ++mi) { af[mi][0] = RDA(bufA, mi, 0); af[mi][1] = RDA(bufA, mi, 1); }
#pragma unroll
    for (int ni = 0; ni < 2; ++ni) { bf[ni][0] = RDB(bufB, ni, 0); bf[ni][1] = RDB(bufB, ni, 1); }
    if (t + 1 < nk) { SB(t + 1, nbN, 1); SB(t + 1, nbN, 2); }
    __builtin_amdgcn_s_barrier();
    asm volatile("s_waitcnt lgkmcnt(0)" ::: "memory");
    __builtin_amdgcn_sched_barrier(0);
    __builtin_amdgcn_s_setprio(1);
#pragma unroll
    for (int mi = 0; mi < 4; ++mi)
#pragma unroll
      for (int ni = 0; ni < 2; ++ni)
#pragma unroll
        for (int kk = 0; kk < 2; ++kk)
          acc[mi][ni] = __builtin_amdgcn_mfma_f32_16x16x32_bf16(af[mi][kk], bf[ni][kk], acc[mi][ni], 0, 0, 0);
    __builtin_amdgcn_s_setprio(0);
    __builtin_amdgcn_s_barrier();

    // ---- P2: m-lo x n{2} ----
    bf[2][0] = RDB(bufB, 2, 0); bf[2][1] = RDB(bufB, 2, 1);
    if (t + 2 < nk) { SA(t + 2, nbC, 0); SA(t + 2, nbC, 2); }
    __builtin_amdgcn_s_barrier();
    asm volatile("s_waitcnt lgkmcnt(0)" ::: "memory");
    __builtin_amdgcn_sched_barrier(0);
    __builtin_amdgcn_s_setprio(1);
#pragma unroll
    for (int mi = 0; mi < 4; ++mi)
#pragma unroll
      for (int kk = 0; kk < 2; ++kk)
        acc[mi][2] = __builtin_amdgcn_mfma_f32_16x16x32_bf16(af[mi][kk], bf[2][kk], acc[mi][2], 0, 0, 0);
    __builtin_amdgcn_s_setprio(0);
    __builtin_amdgcn_s_barrier();

    // ---- P3: m-hi x n{2} — af[] reused for rows mt+4 ----
#pragma unroll
    for (int mi = 0; mi < 4; ++mi) { af[mi][0] = RDA(bufA, mi + 4, 0); af[mi][1] = RDA(bufA, mi + 4, 1); }
    if (t + 2 < nk) SB(t + 2, nbC, 0);
    __builtin_amdgcn_s_barrier();
    asm volatile("s_waitcnt lgkmcnt(0)" ::: "memory");
    __builtin_amdgcn_sched_barrier(0);
    __builtin_amdgcn_s_setprio(1);
#pragma unroll
    for (int mi = 0; mi < 4; ++mi)
#pragma unroll
      for (int kk = 0; kk < 2; ++kk)
        acc[mi + 4][2] = __builtin_amdgcn_mfma_f32_16x16x32_bf16(af[mi][kk], bf[2][kk], acc[mi + 4][2], 0, 0, 0);
    __builtin_amdgcn_s_setprio(0);
    __builtin_amdgcn_s_barrier();

    // ---- P4: m-hi x n{0,1} — all operands live; stage; counted wait ----
    if (t + 2 < nk) { SA(t + 2, nbC, 1); SA(t + 2, nbC, 3); }
    __builtin_amdgcn_s_setprio(1);
#pragma unroll
    for (int mi = 0; mi < 4; ++mi)
#pragma unroll
      for (int ni = 0; ni < 2; ++ni)
#pragma unroll
        for (int kk = 0; kk < 2; ++kk)
          acc[mi + 4][ni] = __builtin_amdgcn_mfma_f32_16x16x32_bf16(af[mi][kk], bf[ni][kk], acc[mi + 4][ni], 0, 0, 0);
    __builtin_amdgcn_s_setprio(0);
    if (t + 2 < nk) asm volatile("s_waitcnt vmcnt(5)" ::: "memory");  // t+1 fully landed
    else            asm volatile("s_waitcnt vmcnt(0)" ::: "memory");
    __builtin_amdgcn_s_barrier();
  }

  // ---- epilogue pass 1: Q/K columns (gn < 2048), layout ltr[256][200] ----
  const float QSC = 0.125f * 1.44269504f;
  if (n0 < 2048) {
#pragma unroll
    for (int nt = 0; nt < 3; ++nt) {
      int nn = wc * 48 + nt * 16 + col;
      int gn = n0 + nn;
      if (gn < 2048) {
        float bv = bias[gn];
        float sc = (gn < 1024) ? QSC : 1.0f;
#pragma unroll
        for (int mt = 0; mt < 8; ++mt) {
          int mm = wr * 128 + mt * 16 + g * 4;
#pragma unroll
          for (int r = 0; r < 4; ++r)
            ltr[(mm + r) * 200 + nn] = f2bf((acc[mt][nt][r] + bv) * sc);
        }
      }
    }
    __syncthreads();
    // scatter: 256 m-rows x 24 n-chunks (16B each; 400B row stride, 16-aligned)
#pragma unroll
    for (int it = 0; it < 12; ++it) {
      int cid = tid + it * 512;
      int rrow = cid / 24, cc = cid % 24;
      int gn = n0 + cc * 8;
      if (gn < 2048) {
        i32x4 v = *(const i32x4*)((const char*)ltr + rrow * 400 + cc * 16);
        int token = m0 + rrow;
        int bb = token >> 11, ll = token & (L_ - 1);
        int head = (gn & 1023) >> 6, d = gn & 63;
        u16* dst = (gn < 1024) ? Qb : Kb;
        *(i32x4*)(dst + ((size_t)((bb * H_ + head) * L_ + ll)) * 64 + d) = v;
      }
    }
  }
  // ---- epilogue pass 2: V columns (gn >= 2048), layout ltr[192][264] ----
  if (n0 + 191 >= 2048) {
    __syncthreads();                    // pass1 reads done before overwrite
#pragma unroll
    for (int nt = 0; nt < 3; ++nt) {
      int nn = wc * 48 + nt * 16 + col;
      int gn = n0 + nn;
      if (gn >= 2048) {
        float bv = bias[gn];
#pragma unroll
        for (int mt = 0; mt < 8; ++mt) {
          int mm = wr * 128 + mt * 16 + g * 4;
#pragma unroll
          for (int r = 0; r < 4; ++r)
            ltr[nn * 264 + (mm + r)] = f2bf(acc[mt][nt][r] + bv);
        }
      }
    }
    __syncthreads();
    // scatter V: 192 n-rows x 32 m-chunks
#pragma unroll
    for (int it = 0; it < 12; ++it) {
      int cid = tid + it * 512;
      int rrow = cid >> 5, cc = cid & 31;
      int gn = n0 + rrow;
      if (gn >= 2048) {
        i32x4 v = *(const i32x4*)((const char*)ltr + rrow * 528 + cc * 16);
        int head = (gn & 1023) >> 6, d = gn & 63;
        int token0 = m0 + cc * 8;
        int bb = token0 >> 11, ll = token0 & (L_ - 1);
        *(i32x4*)(Vt + ((size_t)((bb * H_ + head) * DH_ + d)) * L_ + ll) = v;
      }
    }
  }
}

// ---------------- bf16 GEMM (R17 verbatim — mode-1 output GEMM) ----------------
__global__ __launch_bounds__(512) void gemm_bf16(
    const u16* __restrict__ A, const u16* __restrict__ Bm, const float* __restrict__ bias,
    int M, int N, int K, int mode,
    u16* __restrict__ Qb, u16* __restrict__ Kb, u16* __restrict__ Vt, float* __restrict__ Cout)
{
  __shared__ char smem[147456];
  const int tid = threadIdx.x;
  const int nwg = gridDim.x;
  int idx = blockIdx.x;
  idx = (idx & 7) * (nwg >> 3) + (idx >> 3);
  const int nbx = N >> 7;
  const int bx = idx % nbx, by = idx / nbx;
  const int m0 = by << 8, n0 = bx << 7;

  const int lane = tid & 63, w = tid >> 6;
  const int g = lane >> 4, col = lane & 15;
  const int wr = w >> 1, wc = w & 1;

  f32x4 acc[4][4];
#pragma unroll
  for (int mt = 0; mt < 4; ++mt)
#pragma unroll
    for (int nt = 0; nt < 4; ++nt) {
      acc[mt][nt][0] = 0.f; acc[mt][nt][1] = 0.f;
      acc[mt][nt][2] = 0.f; acc[mt][nt][3] = 0.f;
    }

  auto STAGE_A = [&](int kt, int nb, int hh) {
    char* dA = smem + nb * 49152;
    const int k0 = kt << 6;
#pragma unroll
    for (int pp = hh * 2; pp < hh * 2 + 2; ++pp) {
      int c = tid + pp * 512;
      int row = c >> 3, cc = c & 7;
      gload16(A + (size_t)(m0 + row) * K + k0 + ((cc ^ (row & 7)) << 3), dA + c * 16);
    }
  };
  auto STAGE_B = [&](int kt, int nb) {
    char* dB = smem + nb * 49152 + 32768;
    const int k0 = kt << 6;
#pragma unroll
    for (int pp = 0; pp < 2; ++pp) {
      int c = tid + pp * 512;
      int row = c >> 3, cc = c & 7;
      gload16(Bm + (size_t)(n0 + row) * K + k0 + ((cc ^ (row & 7)) << 3), dB + c * 16);
    }
  };

  STAGE_A(0, 0, 0); STAGE_A(0, 0, 1); STAGE_B(0, 0);
  STAGE_A(1, 1, 0); STAGE_A(1, 1, 1); STAGE_B(1, 1);
  asm volatile("s_waitcnt vmcnt(6)" ::: "memory");
  __builtin_amdgcn_s_barrier();

  const int nk = K >> 6;
  for (int t = 0; t < nk; ++t) {
    const char* bufA = smem + (t % 3) * 49152;
    const char* bufB = bufA + 32768;
    const bool pf = (t + 2 < nk);
    const int nb2 = (t + 2) % 3;

    bf16x8 af[4][2], bfr[4][2];
    auto RDA = [&](int mt, int kk) {
      int row = wr * 64 + mt * 16 + col;
      return *(const bf16x8*)(bufA + row * 128 + ((((kk << 2) + g) ^ (row & 7)) << 4));
    };
    auto RDB = [&](int nt, int kk) {
      int row = wc * 64 + nt * 16 + col;
      return *(const bf16x8*)(bufB + row * 128 + ((((kk << 2) + g) ^ (row & 7)) << 4));
    };
    auto QUAD = [&](int qm, int qn) {
      __builtin_amdgcn_s_setprio(1);
#pragma unroll
      for (int mi = 0; mi < 2; ++mi)
#pragma unroll
        for (int ni = 0; ni < 2; ++ni)
#pragma unroll
          for (int kk = 0; kk < 2; ++kk)
            acc[qm * 2 + mi][qn * 2 + ni] = __builtin_amdgcn_mfma_f32_16x16x32_bf16(
                af[qm * 2 + mi][kk], bfr[qn * 2 + ni][kk], acc[qm * 2 + mi][qn * 2 + ni], 0, 0, 0);
      __builtin_amdgcn_s_setprio(0);
    };

#pragma unroll
    for (int mi = 0; mi < 2; ++mi) { af[mi][0] = RDA(mi, 0); af[mi][1] = RDA(mi, 1); }
#pragma unroll
    for (int ni = 0; ni < 2; ++ni) { bfr[ni][0] = RDB(ni, 0); bfr[ni][1] = RDB(ni, 1); }
    if (pf) STAGE_A(t + 2, nb2, 0);
    __builtin_amdgcn_s_barrier();
    asm volatile("s_waitcnt lgkmcnt(0)" ::: "memory");
    __builtin_amdgcn_sched_barrier(0);
    QUAD(0, 0);
    __builtin_amdgcn_s_barrier();

#pragma unroll
    for (int ni = 2; ni < 4; ++ni) { bfr[ni][0] = RDB(ni, 0); bfr[ni][1] = RDB(ni, 1); }
    if (pf) STAGE_A(t + 2, nb2, 1);
    __builtin_amdgcn_s_barrier();
    asm volatile("s_waitcnt lgkmcnt(0)" ::: "memory");
    __builtin_amdgcn_sched_barrier(0);
    QUAD(0, 1);
    __builtin_amdgcn_s_barrier();

#pragma unroll
    for (int mi = 2; mi < 4; ++mi) { af[mi][0] = RDA(mi, 0); af[mi][1] = RDA(mi, 1); }
    if (pf) STAGE_B(t + 2, nb2);
    __builtin_amdgcn_s_barrier();
    asm volatile("s_waitcnt lgkmcnt(0)" ::: "memory");
    __builtin_amdgcn_sched_barrier(0);
    QUAD(1, 1);
    __builtin_amdgcn_s_barrier();

    QUAD(1, 0);
    if (pf)              asm volatile("s_waitcnt vmcnt(6)" ::: "memory");
    else if (t + 1 < nk) asm volatile("s_waitcnt vmcnt(0)" ::: "memory");
    __builtin_amdgcn_s_barrier();
  }

#pragma unroll
  for (int nt = 0; nt < 4; ++nt) {
    int gn = n0 + wc * 64 + nt * 16 + col;
    float bv = bias[gn];
#pragma unroll
    for (int mt = 0; mt < 4; ++mt) {
      int mbase = m0 + wr * 64 + mt * 16 + g * 4;
#pragma unroll
      for (int r = 0; r < 4; ++r)
        Cout[(size_t)(mbase + r) * N + gn] = acc[mt][nt][r] + bv;
    }
  }
}

// ---------------- fused temporal flash attention (R21 verbatim — best measured) ----------------
__global__ __launch_bounds__(512, 2) void attn_fwd(
    const u16* __restrict__ Qb, const u16* __restrict__ Kb, const u16* __restrict__ Vt,
    const float* __restrict__ Bk, u16* __restrict__ AO)
{
  __shared__ u16 lK[3][64 * 64];     // [key][dh] swz ^(key&7)   24KB
  __shared__ u16 lV[3][64 * 64];     // [d][key]  swz ^(d&7)     24KB => 48KB

  const int phys = blockIdx.x;            // 512 blocks
  const int xcd = phys & 7, s = phys >> 3;
  const int bh = xcd * 8 + (s >> 3);
  const int pr = s & 7;
  const int qa = pr, qbt = 15 - pr;
  const int b = bh >> 4, h = bh & 15;

  const int tid = threadIdx.x, w = tid >> 6, lane = tid & 63;
  const int g = lane >> 4, q16 = lane & 15;

  const float* Bkb = Bk + (size_t)bh * L_;

  int kcol[2], vcol[4];
#pragma unroll
  for (int kk = 0; kk < 2; ++kk) kcol[kk] = ((kk * 4 + g) ^ (q16 & 7)) << 4;
#pragma unroll
  for (int t = 0; t < 4; ++t)
    vcol[t] = (((2 * t + (g >> 1)) ^ (q16 & 7)) << 4) + (g & 1) * 8;

  const int nkA = (qa + 1) * 2;
  const int nkB = (qbt + 1) * 2;

  auto STAGE = [&](int gst, int nb) {
    const int kt = (gst < nkA) ? gst : gst - nkA;
    const int kg0 = kt * 64;
    const int r8 = tid >> 3, cc = tid & 7;
    gload16(Kb + ((size_t)bh * L_ + kg0 + r8) * 64 + ((cc ^ (r8 & 7)) * 8),
            (char*)lK[nb] + tid * 16);
    gload16(Vt + ((size_t)(bh * 64 + r8)) * L_ + kg0 + ((cc ^ (r8 & 7)) * 8),
            (char*)lV[nb] + tid * 16);
  };

  auto QKBODY = [&](bf16x8 (&qf)[2], float& l_r, float mn,
                    int qrow, int kg0, int cur, s16x4 (&pf)[4]) {
    f32x4 sv[4];
#pragma unroll
    for (int t = 0; t < 4; ++t)
      sv[t] = *(const f32x4*)(Bkb + kg0 + t * 16 + g * 4);

    __builtin_amdgcn_s_setprio(1);
#pragma unroll
    for (int t = 0; t < 4; ++t) {
      const char* krow = (const char*)lK[cur] + t * 2048 + q16 * 128;
#pragma unroll
      for (int kk = 0; kk < 2; ++kk) {
        bf16x8 kf = *(const bf16x8*)(krow + kcol[kk]);
        sv[t] = __builtin_amdgcn_mfma_f32_16x16x32_bf16(kf, qf[kk], sv[t], 0, 0, 0);
      }
    }
    __builtin_amdgcn_s_setprio(0);

    if (kg0 + 63 > qrow) {
      const int qg = qrow + q16;
#pragma unroll
      for (int t = 0; t < 4; ++t)
#pragma unroll
        for (int r = 0; r < 4; ++r)
          sv[t][r] = (kg0 + t * 16 + g * 4 + r <= qg) ? sv[t][r] : -INFINITY;
    }

    float rs = 0.f;
#pragma unroll
    for (int t = 0; t < 4; ++t) {
      s16x4 pp;
#pragma unroll
      for (int r = 0; r < 4; ++r) {
        float pv = exp2_fast(sv[t][r] - mn);
        rs += pv;
        pp[r] = (short)f2bf(pv);
      }
      pf[t] = pp;
    }
    l_r += rs;
  };

  auto PVBODY = [&](f32x4 (&o)[4], s16x4 (&pf)[4], int vb) {
    __builtin_amdgcn_s_setprio(1);
#pragma unroll
    for (int t = 0; t < 4; ++t) {
      const char* vrow = (const char*)lV[vb] + q16 * 128 + vcol[t];
#pragma unroll
      for (int db = 0; db < 4; ++db) {
        s16x4 vf = *(const s16x4*)(vrow + db * 2048);
        o[db] = mfma16(vf, pf[t], o[db]);
      }
    }
    __builtin_amdgcn_s_setprio(0);
  };

  auto EPI = [&](f32x4 (&o)[4], float l_r, int qt) {
    float lt = l_r + __shfl_xor(l_r, 16);
    lt += __shfl_xor(lt, 32);
    float inv = 1.f / lt;
    u16* dst = AO + ((size_t)(b * L_ + qt * 128 + w * 16 + q16)) * DM_ + h * 64 + g * 4;
#pragma unroll
    for (int db = 0; db < 4; ++db) {
      u32x2 pk;
      pk[0] = (u32)f2bf(o[db][0] * inv) | ((u32)f2bf(o[db][1] * inv) << 16);
      pk[1] = (u32)f2bf(o[db][2] * inv) | ((u32)f2bf(o[db][3] * inv) << 16);
      *(u32x2*)(dst + db * 16) = pk;
    }
  };

  STAGE(0, 0);
  asm volatile("s_waitcnt vmcnt(0) lgkmcnt(0)" ::: "memory");
  __builtin_amdgcn_s_barrier();
  __builtin_amdgcn_sched_barrier(0);

  // ================= tile A =================
  {
    const int qrow = qa * 128 + w * 16;
    const int mkt = (qrow + 79) >> 6;
    const float mn = Bkb[qrow + q16] + 8.f;
    bf16x8 qf[2];
    {
      const u16* Qr = Qb + ((size_t)bh * L_ + qrow + q16) * 64;
      qf[0] = *(const bf16x8*)(Qr + g * 8);
      qf[1] = *(const bf16x8*)(Qr + 32 + g * 8);
    }
    float l_r = 0.f;
    f32x4 o[4];
#pragma unroll
    for (int db = 0; db < 4; ++db) {
      o[db][0] = 0.f; o[db][1] = 0.f; o[db][2] = 0.f; o[db][3] = 0.f;
    }
    s16x4 pfP[4];
    int pvb = 0;
    bool pvalid = false;
    for (int st = 0; st < nkA; ++st) {
      const int cur = st % 3;
      STAGE(st + 1, (st + 1) % 3);
      const bool doqk = st < mkt;
      s16x4 pfC[4];
      if (doqk) QKBODY(qf, l_r, mn, qrow, st * 64, cur, pfC);
      if (pvalid) PVBODY(o, pfP, pvb);
      if (doqk) {
#pragma unroll
        for (int t = 0; t < 4; ++t) pfP[t] = pfC[t];
        pvb = cur;
      }
      pvalid = doqk;
      asm volatile("s_waitcnt vmcnt(0) lgkmcnt(0)" ::: "memory");
      __builtin_amdgcn_s_barrier();
      __builtin_amdgcn_sched_barrier(0);
    }
    if (pvalid) PVBODY(o, pfP, pvb);
    EPI(o, l_r, qa);
  }
  __builtin_amdgcn_s_barrier();

  // ================= tile B =================
  {
    const int qrow = qbt * 128 + w * 16;
    const int mkt = (qrow + 79) >> 6;
    const float mn = Bkb[qrow + q16] + 8.f;
    bf16x8 qf[2];
    {
      const u16* Qr = Qb + ((size_t)bh * L_ + qrow + q16) * 64;
      qf[0] = *(const bf16x8*)(Qr + g * 8);
      qf[1] = *(const bf16x8*)(Qr + 32 + g * 8);
    }
    float l_r = 0.f;
    f32x4 o[4];
#pragma unroll
    for (int db = 0; db < 4; ++db) {
      o[db][0] = 0.f; o[db][1] = 0.f; o[db][2] = 0.f; o[db][3] = 0.f;
    }
    s16x4 pfP[4];
    int pvb = 0;
    bool pvalid = false;
    for (int kt = 0; kt < nkB; ++kt) {
      const int gst = nkA + kt;
      const int cur = gst % 3;
      if (kt + 1 < nkB) STAGE(gst + 1, (gst + 1) % 3);
      const bool doqk = kt < mkt;
      s16x4 pfC[4];
      if (doqk) QKBODY(qf, l_r, mn, qrow, kt * 64, cur, pfC);
      if (pvalid) PVBODY(o, pfP, pvb);
      if (doqk) {
#pragma unroll
        for (int t = 0; t < 4; ++t) pfP[t] = pfC[t];
        pvb = cur;
      }
      pvalid = doqk;
      if (kt + 1 < nkB) {
        asm volatile("s_waitcnt vmcnt(0) lgkmcnt(0)" ::: "memory");
        __builtin_amdgcn_s_barrier();
        __builtin_amdgcn_sched_barrier(0);
      }
    }
    if (pvalid) PVBODY(o, pfP, pvb);
    EPI(o, l_r, qbt);
  }
}

// ---------------- launcher ----------------
extern "C" void kernel_launch(void* const* d_in, const int* in_sizes, int n_in,
                              void* d_out, int out_size, void* d_ws, size_t ws_size,
                              hipStream_t stream) {
  const float* x    = (const float*)d_in[0];
  const float* ts   = (const float*)d_in[1];
  const float* mk   = (const float*)d_in[2];
  const float* Wqkv = (const float*)d_in[3];
  const float* bqkv = (const float*)d_in[4];
  const float* Wout = (const float*)d_in[5];
  const float* bout = (const float*)d_in[6];
  const float* dec  = (const float*)d_in[7];
  float* out = (float*)d_out;

  char* ws = (char*)d_ws;
  u16* xbf  = (u16*)(ws + 0);
  u16* wqbf = (u16*)(ws + 16777216);
  u16* wobf = (u16*)(ws + 23068672);
  u16* Qb   = (u16*)(ws + 25165824);
  u16* Kb   = (u16*)(ws + 41943040);
  u16* Vt   = (u16*)(ws + 58720256);
  u16* AO   = (u16*)(ws + 75497472);
  float* Bk = (float*)(ws + 92274688);   // 64*2048*4 = 512KB

  // cvt + bias fused: 12288 cvt blocks + 512 bias blocks
  cvt3b<<<dim3((NTOT4 + 64 * 2048) / 256), 256, 0, stream>>>(
      x, Wqkv, Wout, xbf, wqbf, wobf, ts, mk, dec, Bk);

  // QKV GEMM: 256x192 tile, grid = (8192/256)*(3072/192) = 32*16 = 512 blocks
  gemm_qkv<<<dim3(512), 512, 0, stream>>>(xbf, wqbf, bqkv, Qb, Kb, Vt);

  attn_fwd<<<dim3(512), 512, 0, stream>>>(Qb, Kb, Vt, Bk, AO);

  // output GEMM: 256x128 tile, grid = (8192/256)*(1024/128) = 256 blocks
  gemm_bf16<<<dim3(256), 512, 0, stream>>>(
      AO, wobf, bout, 8192, 1024, 1024, 1, nullptr, nullptr, nullptr, out);
}